// Round 1
// baseline (1704.982 us; speedup 1.0000x reference)
//
#include <hip/hip_runtime.h>
#include <hip/hip_bf16.h>
#include <math.h>

// ---------------------------------------------------------------------------
// LinSinkhornPRModel: sigmoid(dist2 - dist1) of two Sinkhorn divergences.
// Key simplification: f_aa (the xx self-term) is identical in both divergences
// (same x=td, same a=h) and cancels exactly in dist2-dist1 -> C_xx never built.
// ---------------------------------------------------------------------------

__device__ __forceinline__ void lse_upd(float& m, float& s, float v) {
    float M2 = fmaxf(m, v);
    s = s * __expf(m - M2) + __expf(v - M2);
    m = M2;
}
__device__ __forceinline__ void lse_merge(float& m, float& s, float mo, float so) {
    float M2 = fmaxf(m, mo);
    s = s * __expf(m - M2) + so * __expf(mo - M2);
    m = M2;
}

// ----------------------------- setup kernels -------------------------------

__global__ void k_transpose(const float* __restrict__ W, float* __restrict__ WT) {
    int b = blockIdx.x, t = threadIdx.x;   // WT[k][o] = W[o][k]
    WT[b * 128 + t] = W[t * 128 + b];
}

__global__ void k_log(const float* __restrict__ x, float* __restrict__ y, int n) {
    int i = blockIdx.x * blockDim.x + threadIdx.x;
    if (i < n) y[i] = logf(x[i]);
}

// one block (128 thr) per row: T = X @ W^T, hn = 0.5*||T_row||^2
__global__ __launch_bounds__(128)
void k_transform(const float* __restrict__ X, const float* __restrict__ WT,
                 float* __restrict__ T, float* __restrict__ hn)
{
    __shared__ float xs[128];
    __shared__ float red[2];
    const int r = blockIdx.x, t = threadIdx.x;
    xs[t] = X[(size_t)r * 128 + t];
    __syncthreads();
    float acc = 0.f;
#pragma unroll 8
    for (int k = 0; k < 128; ++k)
        acc = fmaf(xs[k], WT[k * 128 + t], acc);
    T[(size_t)r * 128 + t] = acc;
    float sq = acc * acc;
#pragma unroll
    for (int o = 32; o; o >>= 1) sq += __shfl_down(sq, o);
    if ((t & 63) == 0) red[t >> 6] = sq;
    __syncthreads();
    if (t == 0) hn[r] = 0.5f * (red[0] + red[1]);
}

// ------------------------------ cost GEMM ----------------------------------
// C[i][j] = max(hna[i] + hnb[j] - dot(A_i, B_j), 0)  == 0.5*max(||a-b||^2, 0)
// 128x128 tile, 256 threads, 8x8 micro-tile, K=128 in two 64-chunks.

#define GPAD 132

__global__ __launch_bounds__(256, 2)
void k_cost(const float* __restrict__ A, const float* __restrict__ B,
            const float* __restrict__ hna, const float* __restrict__ hnb,
            float* __restrict__ C, int M)
{
    __shared__ float Ast[64][GPAD];
    __shared__ float Bst[64][GPAD];
    const int tid = threadIdx.x;
    const int tx = tid & 15, ty = tid >> 4;
    const int i0 = blockIdx.y * 128;
    const int j0 = blockIdx.x * 128;

    float acc[8][8];
#pragma unroll
    for (int m = 0; m < 8; ++m)
#pragma unroll
        for (int n = 0; n < 8; ++n) acc[m][n] = 0.f;

    for (int kc = 0; kc < 128; kc += 64) {
#pragma unroll
        for (int l = 0; l < 8; ++l) {
            int f4 = tid + l * 256;          // 0..2047
            int r = f4 >> 4, cg = f4 & 15;
            float4 va = *reinterpret_cast<const float4*>(&A[(size_t)(i0 + r) * 128 + kc + cg * 4]);
            Ast[cg * 4 + 0][r] = va.x; Ast[cg * 4 + 1][r] = va.y;
            Ast[cg * 4 + 2][r] = va.z; Ast[cg * 4 + 3][r] = va.w;
            float4 vb = *reinterpret_cast<const float4*>(&B[(size_t)(j0 + r) * 128 + kc + cg * 4]);
            Bst[cg * 4 + 0][r] = vb.x; Bst[cg * 4 + 1][r] = vb.y;
            Bst[cg * 4 + 2][r] = vb.z; Bst[cg * 4 + 3][r] = vb.w;
        }
        __syncthreads();
#pragma unroll 4
        for (int k = 0; k < 64; ++k) {
            float a[8], b[8];
            *reinterpret_cast<float4*>(&a[0]) = *reinterpret_cast<const float4*>(&Ast[k][ty * 8]);
            *reinterpret_cast<float4*>(&a[4]) = *reinterpret_cast<const float4*>(&Ast[k][ty * 8 + 4]);
            *reinterpret_cast<float4*>(&b[0]) = *reinterpret_cast<const float4*>(&Bst[k][tx * 8]);
            *reinterpret_cast<float4*>(&b[4]) = *reinterpret_cast<const float4*>(&Bst[k][tx * 8 + 4]);
#pragma unroll
            for (int m = 0; m < 8; ++m)
#pragma unroll
                for (int n = 0; n < 8; ++n)
                    acc[m][n] = fmaf(a[m], b[n], acc[m][n]);
        }
        __syncthreads();
    }
#pragma unroll
    for (int m = 0; m < 8; ++m) {
        int i = i0 + ty * 8 + m;
        float ha = hna[i];
        float ov[8];
#pragma unroll
        for (int n = 0; n < 8; ++n)
            ov[n] = fmaxf(ha + hnb[j0 + tx * 8 + n] - acc[m][n], 0.f);
        *reinterpret_cast<float4*>(&C[(size_t)i * M + j0 + tx * 8])     = *reinterpret_cast<float4*>(&ov[0]);
        *reinterpret_cast<float4*>(&C[(size_t)i * M + j0 + tx * 8 + 4]) = *reinterpret_cast<float4*>(&ov[4]);
    }
}

// ----------------------------- softmin kernels -----------------------------
// out[i] = alpha*fold[i] + beta * ( -eps * lse_j( w0[j] + g[j]*gsc - C[i][j]*ie ) )

struct SmRow {
    const float* C; const float* w0; const float* g; const float* fold; float* out;
};

__global__ __launch_bounds__(256)
void k_sm_row(SmRow A0, SmRow A1, int M, float gsc, float ie, float eps,
              float alpha, float beta)
{
    const SmRow A = blockIdx.z ? A1 : A0;
    const size_t i = blockIdx.x;
    const float4* row = reinterpret_cast<const float4*>(A.C + i * M);
    const float4* w4  = reinterpret_cast<const float4*>(A.w0);
    const float4* g4  = reinterpret_cast<const float4*>(A.g);
    const int nf4 = M >> 2;
    float m = -INFINITY, s = 0.f;
    for (int j = threadIdx.x; j < nf4; j += 256) {
        float4 c = row[j], wv = w4[j], gv = g4[j];
        lse_upd(m, s, wv.x + gv.x * gsc - c.x * ie);
        lse_upd(m, s, wv.y + gv.y * gsc - c.y * ie);
        lse_upd(m, s, wv.z + gv.z * gsc - c.z * ie);
        lse_upd(m, s, wv.w + gv.w * gsc - c.w * ie);
    }
#pragma unroll
    for (int o = 32; o; o >>= 1) {
        float mo = __shfl_xor(m, o), so = __shfl_xor(s, o);
        lse_merge(m, s, mo, so);
    }
    __shared__ float sm[4], ss[4];
    const int lane = threadIdx.x & 63, w = threadIdx.x >> 6;
    if (lane == 0) { sm[w] = m; ss[w] = s; }
    __syncthreads();
    if (threadIdx.x == 0) {
        for (int q = 1; q < 4; ++q) lse_merge(m, s, sm[q], ss[q]);
        A.out[i] = alpha * A.fold[i] + beta * (-eps * (m + logf(s)));
    }
}

// column direction: partials over row-chunks, then combine.
struct SmCol {
    const float* C; const float* w0; const float* f; const float* gold;
    float* pm; float* ps; float* out;
};

__global__ __launch_bounds__(256)
void k_sm_col_part(SmCol A0, SmCol A1, int M, float fsc, float ie, int rpc)
{
    const SmCol A = blockIdx.z ? A1 : A0;
    const int j4 = blockIdx.x * 256 + threadIdx.x;   // float4 column index
    const int i0 = blockIdx.y * rpc;
    const float4* C4 = reinterpret_cast<const float4*>(A.C);
    const int M4 = M >> 2;
    float4 m = make_float4(-INFINITY, -INFINITY, -INFINITY, -INFINITY);
    float4 s = make_float4(0.f, 0.f, 0.f, 0.f);
    for (int rr = 0; rr < rpc; ++rr) {
        int i = i0 + rr;
        float wv = A.w0[i] + A.f[i] * fsc;
        float4 c = C4[(size_t)i * M4 + j4];
        lse_upd(m.x, s.x, wv - c.x * ie);
        lse_upd(m.y, s.y, wv - c.y * ie);
        lse_upd(m.z, s.z, wv - c.z * ie);
        lse_upd(m.w, s.w, wv - c.w * ie);
    }
    size_t o = (size_t)blockIdx.y * M + (size_t)j4 * 4;
    *reinterpret_cast<float4*>(A.pm + o) = m;
    *reinterpret_cast<float4*>(A.ps + o) = s;
}

__global__ __launch_bounds__(256)
void k_sm_col_comb(SmCol A0, SmCol A1, int M, int nchunk, float eps,
                   float alpha, float beta)
{
    const SmCol A = blockIdx.z ? A1 : A0;
    const int j = blockIdx.x * 256 + threadIdx.x;
    float m = -INFINITY, s = 0.f;
    for (int c = 0; c < nchunk; ++c)
        lse_merge(m, s, A.pm[(size_t)c * M + j], A.ps[(size_t)c * M + j]);
    A.out[j] = alpha * A.gold[j] + beta * (-eps * (m + logf(s)));
}

// ------------------------------ final reduce -------------------------------

__global__ __launch_bounds__(1024)
void k_final(const float* __restrict__ h, const float* __restrict__ hi,
             const float* __restrict__ hj,
             const float* __restrict__ f1f, const float* __restrict__ f2f,
             const float* __restrict__ g1f, const float* __restrict__ gb1f,
             const float* __restrict__ g2f, const float* __restrict__ gb2f,
             int N, int M, float* __restrict__ out)
{
    float acc = 0.f;
    for (int i = threadIdx.x; i < N; i += 1024)
        acc += h[i] * (f2f[i] - f1f[i]);
    for (int j = threadIdx.x; j < M; j += 1024)
        acc += hj[j] * (g2f[j] - gb2f[j]) - hi[j] * (g1f[j] - gb1f[j]);
#pragma unroll
    for (int o = 32; o; o >>= 1) acc += __shfl_xor(acc, o);
    __shared__ float red[16];
    const int lane = threadIdx.x & 63, w = threadIdx.x >> 6;
    if (lane == 0) red[w] = acc;
    __syncthreads();
    if (threadIdx.x == 0) {
        float t = 0.f;
        for (int q = 0; q < 16; ++q) t += red[q];
        out[0] = 1.f / (1.f + expf(-t));   // SCALING_FACTOR = 1
    }
}

// ------------------------------ orchestration ------------------------------

extern "C" void kernel_launch(void* const* d_in, const int* in_sizes, int n_in,
                              void* d_out, int out_size, void* d_ws, size_t ws_size,
                              hipStream_t stream)
{
    const float* d  = (const float*)d_in[0];
    const float* si = (const float*)d_in[1];
    const float* sj = (const float*)d_in[2];
    const float* h  = (const float*)d_in[3];
    const float* hi = (const float*)d_in[4];
    const float* hj = (const float*)d_in[5];
    const float* W  = (const float*)d_in[6];
    float* out = (float*)d_out;

    const int N = in_sizes[3];   // 4096
    const int M = in_sizes[4];   // 2048
    const int RPC = 16;          // rows per chunk for column softmin

    float* ws = (float*)d_ws;
    size_t off = 0;
    auto alloc = [&](size_t n) { float* p = ws + off; off += (n + 63) & ~(size_t)63; return p; };

    float* WT  = alloc(128 * 128);
    float* td  = alloc((size_t)N * 128);
    float* tsi = alloc((size_t)M * 128);
    float* tsj = alloc((size_t)M * 128);
    float* hnx = alloc(N); float* hni = alloc(M); float* hnj = alloc(M);
    float* la  = alloc(N); float* lbi = alloc(M); float* lbj = alloc(M);
    float* f1[2]  = { alloc(N), alloc(N) };
    float* g1[2]  = { alloc(M), alloc(M) };
    float* gb1[2] = { alloc(M), alloc(M) };
    float* f2[2]  = { alloc(N), alloc(N) };
    float* g2[2]  = { alloc(M), alloc(M) };
    float* gb2[2] = { alloc(M), alloc(M) };
    float* f1f = alloc(N); float* g1f = alloc(M); float* gb1f = alloc(M);
    float* f2f = alloc(N); float* g2f = alloc(M); float* gb2f = alloc(M);
    float* C1  = alloc((size_t)N * M);
    float* C2  = alloc((size_t)N * M);
    float* Cy1 = alloc((size_t)M * M);
    float* Cy2 = alloc((size_t)M * M);
    float* pm1 = alloc((size_t)(N / RPC) * M);
    float* ps1 = alloc((size_t)(N / RPC) * M);
    float* pm2 = alloc((size_t)(N / RPC) * M);
    float* ps2 = alloc((size_t)(N / RPC) * M);
    (void)ws_size; (void)n_in; (void)out_size;

    // setup
    k_transpose<<<128, 128, 0, stream>>>(W, WT);
    k_transform<<<N, 128, 0, stream>>>(d,  WT, td,  hnx);
    k_transform<<<M, 128, 0, stream>>>(si, WT, tsi, hni);
    k_transform<<<M, 128, 0, stream>>>(sj, WT, tsj, hnj);
    k_log<<<(N + 255) / 256, 256, 0, stream>>>(h,  la,  N);
    k_log<<<(M + 255) / 256, 256, 0, stream>>>(hi, lbi, M);
    k_log<<<(M + 255) / 256, 256, 0, stream>>>(hj, lbj, M);

    dim3 gxy(M / 128, N / 128);
    dim3 gyy(M / 128, M / 128);
    k_cost<<<gxy, 256, 0, stream>>>(td,  tsi, hnx, hni, C1,  M);
    k_cost<<<gxy, 256, 0, stream>>>(td,  tsj, hnx, hnj, C2,  M);
    k_cost<<<gyy, 256, 0, stream>>>(tsi, tsi, hni, hni, Cy1, M);
    k_cost<<<gyy, 256, 0, stream>>>(tsj, tsj, hnj, hnj, Cy2, M);

    // eps schedule (geomloss annealing)
    double epsl[16]; int ne = 0;
    for (double sg = 32.0; sg > 0.05; sg *= 0.5) epsl[ne++] = sg * sg;
    epsl[ne++] = 0.05 * 0.05;   // ne == 11

    int cur = 0;
    for (int r = 0; r <= ne + 1; ++r) {
        const bool init = (r == 0), fin = (r == ne + 1);
        const float eps = (float)(init ? epsl[0] : (fin ? epsl[ne - 1] : epsl[r - 1]));
        const float ie  = 1.0f / eps;
        const float gsc = init ? 0.0f : ie;
        const float alpha = (init || fin) ? 0.0f : 0.5f;
        const float beta  = (init || fin) ? 1.0f : 0.5f;
        const int nxt = cur ^ 1;

        // f updates (row softmin over C_xy), both divergences in one launch
        SmRow rx0 = { C1, lbi, g1[cur], f1[cur], fin ? f1f : f1[nxt] };
        SmRow rx1 = { C2, lbj, g2[cur], f2[cur], fin ? f2f : f2[nxt] };
        k_sm_row<<<dim3(N, 1, 2), 256, 0, stream>>>(rx0, rx1, M, gsc, ie, eps, alpha, beta);

        // g updates (column softmin over C_xy)
        SmCol c0 = { C1, la, f1[cur], g1[cur], pm1, ps1, fin ? g1f : g1[nxt] };
        SmCol c1 = { C2, la, f2[cur], g2[cur], pm2, ps2, fin ? g2f : g2[nxt] };
        k_sm_col_part<<<dim3(M / 1024, N / RPC, 2), 256, 0, stream>>>(c0, c1, M, gsc, ie, RPC);
        k_sm_col_comb<<<dim3(M / 256, 1, 2), 256, 0, stream>>>(c0, c1, M, N / RPC, eps, alpha, beta);

        // g_bb updates (row softmin over C_yy)
        SmRow ry0 = { Cy1, lbi, gb1[cur], gb1[cur], fin ? gb1f : gb1[nxt] };
        SmRow ry1 = { Cy2, lbj, gb2[cur], gb2[cur], fin ? gb2f : gb2[nxt] };
        k_sm_row<<<dim3(M, 1, 2), 256, 0, stream>>>(ry0, ry1, M, gsc, ie, eps, alpha, beta);

        if (!fin) cur = nxt;
    }

    k_final<<<1, 1024, 0, stream>>>(h, hi, hj, f1f, f2f, g1f, gb1f, g2f, gb2f, N, M, out);
}

// Round 2
// 712.605 us; speedup vs baseline: 2.3926x; 2.3926x over previous
//
#include <hip/hip_runtime.h>
#include <hip/hip_bf16.h>
#include <math.h>

// ---------------------------------------------------------------------------
// LinSinkhornPRModel: sigmoid(dist2 - dist1) of two Sinkhorn divergences.
// Key simplification: f_aa (the xx self-term) is identical in both divergences
// (same x=td, same a=h) and cancels exactly in dist2-dist1 -> C_xx never built.
// R1: parallelized k_sm_col_comb (was 16 blocks / 256-deep serial merge chain
//     = 66% of runtime at 0.6% occupancy); RPC 16->32 halves partial traffic.
// ---------------------------------------------------------------------------

__device__ __forceinline__ void lse_upd(float& m, float& s, float v) {
    float M2 = fmaxf(m, v);
    s = s * __expf(m - M2) + __expf(v - M2);
    m = M2;
}
__device__ __forceinline__ void lse_merge(float& m, float& s, float mo, float so) {
    float M2 = fmaxf(m, mo);
    s = s * __expf(m - M2) + so * __expf(mo - M2);
    m = M2;
}

// ----------------------------- setup kernels -------------------------------

__global__ void k_transpose(const float* __restrict__ W, float* __restrict__ WT) {
    int b = blockIdx.x, t = threadIdx.x;   // WT[k][o] = W[o][k]
    WT[b * 128 + t] = W[t * 128 + b];
}

__global__ void k_log(const float* __restrict__ x, float* __restrict__ y, int n) {
    int i = blockIdx.x * blockDim.x + threadIdx.x;
    if (i < n) y[i] = logf(x[i]);
}

// one block (128 thr) per row: T = X @ W^T, hn = 0.5*||T_row||^2
__global__ __launch_bounds__(128)
void k_transform(const float* __restrict__ X, const float* __restrict__ WT,
                 float* __restrict__ T, float* __restrict__ hn)
{
    __shared__ float xs[128];
    __shared__ float red[2];
    const int r = blockIdx.x, t = threadIdx.x;
    xs[t] = X[(size_t)r * 128 + t];
    __syncthreads();
    float acc = 0.f;
#pragma unroll 8
    for (int k = 0; k < 128; ++k)
        acc = fmaf(xs[k], WT[k * 128 + t], acc);
    T[(size_t)r * 128 + t] = acc;
    float sq = acc * acc;
#pragma unroll
    for (int o = 32; o; o >>= 1) sq += __shfl_down(sq, o);
    if ((t & 63) == 0) red[t >> 6] = sq;
    __syncthreads();
    if (t == 0) hn[r] = 0.5f * (red[0] + red[1]);
}

// ------------------------------ cost GEMM ----------------------------------
// C[i][j] = max(hna[i] + hnb[j] - dot(A_i, B_j), 0)  == 0.5*max(||a-b||^2, 0)

#define GPAD 132

__global__ __launch_bounds__(256, 2)
void k_cost(const float* __restrict__ A, const float* __restrict__ B,
            const float* __restrict__ hna, const float* __restrict__ hnb,
            float* __restrict__ C, int M)
{
    __shared__ float Ast[64][GPAD];
    __shared__ float Bst[64][GPAD];
    const int tid = threadIdx.x;
    const int tx = tid & 15, ty = tid >> 4;
    const int i0 = blockIdx.y * 128;
    const int j0 = blockIdx.x * 128;

    float acc[8][8];
#pragma unroll
    for (int m = 0; m < 8; ++m)
#pragma unroll
        for (int n = 0; n < 8; ++n) acc[m][n] = 0.f;

    for (int kc = 0; kc < 128; kc += 64) {
#pragma unroll
        for (int l = 0; l < 8; ++l) {
            int f4 = tid + l * 256;          // 0..2047
            int r = f4 >> 4, cg = f4 & 15;
            float4 va = *reinterpret_cast<const float4*>(&A[(size_t)(i0 + r) * 128 + kc + cg * 4]);
            Ast[cg * 4 + 0][r] = va.x; Ast[cg * 4 + 1][r] = va.y;
            Ast[cg * 4 + 2][r] = va.z; Ast[cg * 4 + 3][r] = va.w;
            float4 vb = *reinterpret_cast<const float4*>(&B[(size_t)(j0 + r) * 128 + kc + cg * 4]);
            Bst[cg * 4 + 0][r] = vb.x; Bst[cg * 4 + 1][r] = vb.y;
            Bst[cg * 4 + 2][r] = vb.z; Bst[cg * 4 + 3][r] = vb.w;
        }
        __syncthreads();
#pragma unroll 4
        for (int k = 0; k < 64; ++k) {
            float a[8], b[8];
            *reinterpret_cast<float4*>(&a[0]) = *reinterpret_cast<const float4*>(&Ast[k][ty * 8]);
            *reinterpret_cast<float4*>(&a[4]) = *reinterpret_cast<const float4*>(&Ast[k][ty * 8 + 4]);
            *reinterpret_cast<float4*>(&b[0]) = *reinterpret_cast<const float4*>(&Bst[k][tx * 8]);
            *reinterpret_cast<float4*>(&b[4]) = *reinterpret_cast<const float4*>(&Bst[k][tx * 8 + 4]);
#pragma unroll
            for (int m = 0; m < 8; ++m)
#pragma unroll
                for (int n = 0; n < 8; ++n)
                    acc[m][n] = fmaf(a[m], b[n], acc[m][n]);
        }
        __syncthreads();
    }
#pragma unroll
    for (int m = 0; m < 8; ++m) {
        int i = i0 + ty * 8 + m;
        float ha = hna[i];
        float ov[8];
#pragma unroll
        for (int n = 0; n < 8; ++n)
            ov[n] = fmaxf(ha + hnb[j0 + tx * 8 + n] - acc[m][n], 0.f);
        *reinterpret_cast<float4*>(&C[(size_t)i * M + j0 + tx * 8])     = *reinterpret_cast<float4*>(&ov[0]);
        *reinterpret_cast<float4*>(&C[(size_t)i * M + j0 + tx * 8 + 4]) = *reinterpret_cast<float4*>(&ov[4]);
    }
}

// ----------------------------- softmin kernels -----------------------------
// out[i] = alpha*fold[i] + beta * ( -eps * lse_j( w0[j] + g[j]*gsc - C[i][j]*ie ) )

struct SmRow {
    const float* C; const float* w0; const float* g; const float* fold; float* out;
};

__global__ __launch_bounds__(256)
void k_sm_row(SmRow A0, SmRow A1, int M, float gsc, float ie, float eps,
              float alpha, float beta)
{
    const SmRow A = blockIdx.z ? A1 : A0;
    const size_t i = blockIdx.x;
    const float4* row = reinterpret_cast<const float4*>(A.C + i * M);
    const float4* w4  = reinterpret_cast<const float4*>(A.w0);
    const float4* g4  = reinterpret_cast<const float4*>(A.g);
    const int nf4 = M >> 2;
    float m = -INFINITY, s = 0.f;
    for (int j = threadIdx.x; j < nf4; j += 256) {
        float4 c = row[j], wv = w4[j], gv = g4[j];
        lse_upd(m, s, wv.x + gv.x * gsc - c.x * ie);
        lse_upd(m, s, wv.y + gv.y * gsc - c.y * ie);
        lse_upd(m, s, wv.z + gv.z * gsc - c.z * ie);
        lse_upd(m, s, wv.w + gv.w * gsc - c.w * ie);
    }
#pragma unroll
    for (int o = 32; o; o >>= 1) {
        float mo = __shfl_xor(m, o), so = __shfl_xor(s, o);
        lse_merge(m, s, mo, so);
    }
    __shared__ float sm[4], ss[4];
    const int lane = threadIdx.x & 63, w = threadIdx.x >> 6;
    if (lane == 0) { sm[w] = m; ss[w] = s; }
    __syncthreads();
    if (threadIdx.x == 0) {
        for (int q = 1; q < 4; ++q) lse_merge(m, s, sm[q], ss[q]);
        A.out[i] = alpha * A.fold[i] + beta * (-eps * (m + logf(s)));
    }
}

// column direction: partials over row-chunks, then parallel combine.
struct SmCol {
    const float* C; const float* w0; const float* f; const float* gold;
    float* pm; float* ps; float* out;
};

__global__ __launch_bounds__(256)
void k_sm_col_part(SmCol A0, SmCol A1, int M, float fsc, float ie, int rpc)
{
    const SmCol A = blockIdx.z ? A1 : A0;
    const int j4 = blockIdx.x * 256 + threadIdx.x;   // float4 column index
    const int i0 = blockIdx.y * rpc;
    const float4* C4 = reinterpret_cast<const float4*>(A.C);
    const int M4 = M >> 2;
    float4 m = make_float4(-INFINITY, -INFINITY, -INFINITY, -INFINITY);
    float4 s = make_float4(0.f, 0.f, 0.f, 0.f);
    for (int rr = 0; rr < rpc; ++rr) {
        int i = i0 + rr;
        float wv = A.w0[i] + A.f[i] * fsc;
        float4 c = C4[(size_t)i * M4 + j4];
        lse_upd(m.x, s.x, wv - c.x * ie);
        lse_upd(m.y, s.y, wv - c.y * ie);
        lse_upd(m.z, s.z, wv - c.z * ie);
        lse_upd(m.w, s.w, wv - c.w * ie);
    }
    size_t o = (size_t)blockIdx.y * M + (size_t)j4 * 4;
    *reinterpret_cast<float4*>(A.pm + o) = m;
    *reinterpret_cast<float4*>(A.ps + o) = s;
}

// Parallel combine: 16 threads per column. Thread (jl = t&15, cg = t>>4)
// merges chunks {cg, cg+16, ...}; shfl_xor(16,32) merges the 4 cg-groups in a
// wave; LDS merges the 4 waves. Grid (M/16, 1, 2).
__global__ __launch_bounds__(256)
void k_sm_col_comb(SmCol A0, SmCol A1, int M, int nchunk, float eps,
                   float alpha, float beta)
{
    const SmCol A = blockIdx.z ? A1 : A0;
    const int jl = threadIdx.x & 15;
    const int j  = blockIdx.x * 16 + jl;
    const int cg = threadIdx.x >> 4;          // 0..15
    float m = -INFINITY, s = 0.f;
    for (int c = cg; c < nchunk; c += 16)
        lse_merge(m, s, A.pm[(size_t)c * M + j], A.ps[(size_t)c * M + j]);
#pragma unroll
    for (int o = 16; o <= 32; o <<= 1) {
        float mo = __shfl_xor(m, o), so = __shfl_xor(s, o);
        lse_merge(m, s, mo, so);
    }
    __shared__ float smm[4][16], sss[4][16];
    const int lane = threadIdx.x & 63, w = threadIdx.x >> 6;
    if (lane < 16) { smm[w][lane] = m; sss[w][lane] = s; }
    __syncthreads();
    if (threadIdx.x < 16) {
        m = smm[0][jl]; s = sss[0][jl];
        for (int q = 1; q < 4; ++q) lse_merge(m, s, smm[q][jl], sss[q][jl]);
        A.out[j] = alpha * A.gold[j] + beta * (-eps * (m + logf(s)));
    }
}

// ------------------------------ final reduce -------------------------------

__global__ __launch_bounds__(1024)
void k_final(const float* __restrict__ h, const float* __restrict__ hi,
             const float* __restrict__ hj,
             const float* __restrict__ f1f, const float* __restrict__ f2f,
             const float* __restrict__ g1f, const float* __restrict__ gb1f,
             const float* __restrict__ g2f, const float* __restrict__ gb2f,
             int N, int M, float* __restrict__ out)
{
    float acc = 0.f;
    for (int i = threadIdx.x; i < N; i += 1024)
        acc += h[i] * (f2f[i] - f1f[i]);
    for (int j = threadIdx.x; j < M; j += 1024)
        acc += hj[j] * (g2f[j] - gb2f[j]) - hi[j] * (g1f[j] - gb1f[j]);
#pragma unroll
    for (int o = 32; o; o >>= 1) acc += __shfl_xor(acc, o);
    __shared__ float red[16];
    const int lane = threadIdx.x & 63, w = threadIdx.x >> 6;
    if (lane == 0) red[w] = acc;
    __syncthreads();
    if (threadIdx.x == 0) {
        float t = 0.f;
        for (int q = 0; q < 16; ++q) t += red[q];
        out[0] = 1.f / (1.f + expf(-t));   // SCALING_FACTOR = 1
    }
}

// ------------------------------ orchestration ------------------------------

extern "C" void kernel_launch(void* const* d_in, const int* in_sizes, int n_in,
                              void* d_out, int out_size, void* d_ws, size_t ws_size,
                              hipStream_t stream)
{
    const float* d  = (const float*)d_in[0];
    const float* si = (const float*)d_in[1];
    const float* sj = (const float*)d_in[2];
    const float* h  = (const float*)d_in[3];
    const float* hi = (const float*)d_in[4];
    const float* hj = (const float*)d_in[5];
    const float* W  = (const float*)d_in[6];
    float* out = (float*)d_out;

    const int N = in_sizes[3];   // 4096
    const int M = in_sizes[4];   // 2048
    const int RPC = 32;          // rows per chunk for column softmin

    float* ws = (float*)d_ws;
    size_t off = 0;
    auto alloc = [&](size_t n) { float* p = ws + off; off += (n + 63) & ~(size_t)63; return p; };

    float* WT  = alloc(128 * 128);
    float* td  = alloc((size_t)N * 128);
    float* tsi = alloc((size_t)M * 128);
    float* tsj = alloc((size_t)M * 128);
    float* hnx = alloc(N); float* hni = alloc(M); float* hnj = alloc(M);
    float* la  = alloc(N); float* lbi = alloc(M); float* lbj = alloc(M);
    float* f1[2]  = { alloc(N), alloc(N) };
    float* g1[2]  = { alloc(M), alloc(M) };
    float* gb1[2] = { alloc(M), alloc(M) };
    float* f2[2]  = { alloc(N), alloc(N) };
    float* g2[2]  = { alloc(M), alloc(M) };
    float* gb2[2] = { alloc(M), alloc(M) };
    float* f1f = alloc(N); float* g1f = alloc(M); float* gb1f = alloc(M);
    float* f2f = alloc(N); float* g2f = alloc(M); float* gb2f = alloc(M);
    float* C1  = alloc((size_t)N * M);
    float* C2  = alloc((size_t)N * M);
    float* Cy1 = alloc((size_t)M * M);
    float* Cy2 = alloc((size_t)M * M);
    float* pm1 = alloc((size_t)(N / RPC) * M);
    float* ps1 = alloc((size_t)(N / RPC) * M);
    float* pm2 = alloc((size_t)(N / RPC) * M);
    float* ps2 = alloc((size_t)(N / RPC) * M);
    (void)ws_size; (void)n_in; (void)out_size;

    // setup
    k_transpose<<<128, 128, 0, stream>>>(W, WT);
    k_transform<<<N, 128, 0, stream>>>(d,  WT, td,  hnx);
    k_transform<<<M, 128, 0, stream>>>(si, WT, tsi, hni);
    k_transform<<<M, 128, 0, stream>>>(sj, WT, tsj, hnj);
    k_log<<<(N + 255) / 256, 256, 0, stream>>>(h,  la,  N);
    k_log<<<(M + 255) / 256, 256, 0, stream>>>(hi, lbi, M);
    k_log<<<(M + 255) / 256, 256, 0, stream>>>(hj, lbj, M);

    dim3 gxy(M / 128, N / 128);
    dim3 gyy(M / 128, M / 128);
    k_cost<<<gxy, 256, 0, stream>>>(td,  tsi, hnx, hni, C1,  M);
    k_cost<<<gxy, 256, 0, stream>>>(td,  tsj, hnx, hnj, C2,  M);
    k_cost<<<gyy, 256, 0, stream>>>(tsi, tsi, hni, hni, Cy1, M);
    k_cost<<<gyy, 256, 0, stream>>>(tsj, tsj, hnj, hnj, Cy2, M);

    // eps schedule (geomloss annealing)
    double epsl[16]; int ne = 0;
    for (double sg = 32.0; sg > 0.05; sg *= 0.5) epsl[ne++] = sg * sg;
    epsl[ne++] = 0.05 * 0.05;   // ne == 11

    int cur = 0;
    for (int r = 0; r <= ne + 1; ++r) {
        const bool init = (r == 0), fin = (r == ne + 1);
        const float eps = (float)(init ? epsl[0] : (fin ? epsl[ne - 1] : epsl[r - 1]));
        const float ie  = 1.0f / eps;
        const float gsc = init ? 0.0f : ie;
        const float alpha = (init || fin) ? 0.0f : 0.5f;
        const float beta  = (init || fin) ? 1.0f : 0.5f;
        const int nxt = cur ^ 1;

        // f updates (row softmin over C_xy), both divergences in one launch
        SmRow rx0 = { C1, lbi, g1[cur], f1[cur], fin ? f1f : f1[nxt] };
        SmRow rx1 = { C2, lbj, g2[cur], f2[cur], fin ? f2f : f2[nxt] };
        k_sm_row<<<dim3(N, 1, 2), 256, 0, stream>>>(rx0, rx1, M, gsc, ie, eps, alpha, beta);

        // g updates (column softmin over C_xy)
        SmCol c0 = { C1, la, f1[cur], g1[cur], pm1, ps1, fin ? g1f : g1[nxt] };
        SmCol c1 = { C2, la, f2[cur], g2[cur], pm2, ps2, fin ? g2f : g2[nxt] };
        k_sm_col_part<<<dim3(M / 1024, N / RPC, 2), 256, 0, stream>>>(c0, c1, M, gsc, ie, RPC);
        k_sm_col_comb<<<dim3(M / 16, 1, 2), 256, 0, stream>>>(c0, c1, M, N / RPC, eps, alpha, beta);

        // g_bb updates (row softmin over C_yy)
        SmRow ry0 = { Cy1, lbi, gb1[cur], gb1[cur], fin ? gb1f : gb1[nxt] };
        SmRow ry1 = { Cy2, lbj, gb2[cur], gb2[cur], fin ? gb2f : gb2[nxt] };
        k_sm_row<<<dim3(M, 1, 2), 256, 0, stream>>>(ry0, ry1, M, gsc, ie, eps, alpha, beta);

        if (!fin) cur = nxt;
    }

    k_final<<<1, 1024, 0, stream>>>(h, hi, hj, f1f, f2f, g1f, gb1f, g2f, gb2f, N, M, out);
}

// Round 3
// 459.531 us; speedup vs baseline: 3.7103x; 1.5507x over previous
//
#include <hip/hip_runtime.h>
#include <math.h>

// ---------------------------------------------------------------------------
// LinSinkhornPRModel: sigmoid(dist2 - dist1) of two Sinkhorn divergences.
//   - f_aa self-term cancels in dist2-dist1 -> C_xx never built.
//   - R2: one fused kernel per round (CT materialized so col-softmin = row
//     softmin over CT); log2-domain LSE; bf16-split MFMA cost GEMM;
//     weight vectors (log b + v/eps) chained between rounds.
// ---------------------------------------------------------------------------

typedef __attribute__((ext_vector_type(8))) short short8;
typedef __attribute__((ext_vector_type(4))) float f32x4;

#define LOG2E 1.4426950408889634
#define LN2   0.6931471805599453

__device__ __forceinline__ float exp2fast(float x){
#if __has_builtin(__builtin_amdgcn_exp2f)
    return __builtin_amdgcn_exp2f(x);
#else
    return exp2f(x);
#endif
}
__device__ __forceinline__ void lse2_upd(float& m, float& s, float v){
    float M2 = fmaxf(m, v);
    s = s * exp2fast(m - M2) + exp2fast(v - M2);
    m = M2;
}
__device__ __forceinline__ void lse2_merge(float& m, float& s, float mo, float so){
    float M2 = fmaxf(m, mo);
    s = s * exp2fast(m - M2) + so * exp2fast(mo - M2);
    m = M2;
}
__device__ __forceinline__ unsigned short f2bf(float x){
    unsigned u = __float_as_uint(x);
    unsigned r = u + 0x7fffu + ((u >> 16) & 1u);
    return (unsigned short)(r >> 16);
}
__device__ __forceinline__ float bf2f(unsigned short h){
    return __uint_as_float(((unsigned)h) << 16);
}

// ----------------------------- setup kernels -------------------------------

__global__ void k_transposeW(const float* __restrict__ W, float* __restrict__ WT){
    int b = blockIdx.x, t = threadIdx.x;   // WT[k][o] = W[o][k]
    WT[b * 128 + t] = W[t * 128 + b];
}

// 8 rows per block: T = X@W^T; writes bf16 split (th, tl) and hn = 0.5*||T||^2
__global__ __launch_bounds__(128)
void k_transform_all(const float* __restrict__ d, const float* __restrict__ si,
                     const float* __restrict__ sj, const float* __restrict__ WT,
                     unsigned short* __restrict__ th, unsigned short* __restrict__ tl,
                     float* __restrict__ hn)
{
    __shared__ float xs[8][128];
    __shared__ float red[16];
    const int t = threadIdx.x;
    const int r0 = blockIdx.x * 8;
    const float* src; int sr;
    if (r0 < 4096)      { src = d;  sr = r0; }
    else if (r0 < 6144) { src = si; sr = r0 - 4096; }
    else                { src = sj; sr = r0 - 6144; }
    for (int rr = 0; rr < 8; ++rr)
        xs[rr][t] = src[(size_t)(sr + rr) * 128 + t];
    __syncthreads();
    float acc[8];
#pragma unroll
    for (int rr = 0; rr < 8; ++rr) acc[rr] = 0.f;
    for (int k = 0; k < 128; ++k) {
        float wv = WT[k * 128 + t];
#pragma unroll
        for (int rr = 0; rr < 8; ++rr) acc[rr] = fmaf(xs[rr][k], wv, acc[rr]);
    }
#pragma unroll
    for (int rr = 0; rr < 8; ++rr) {
        float a = acc[rr];
        unsigned short hb = f2bf(a);
        th[(size_t)(r0 + rr) * 128 + t] = hb;
        tl[(size_t)(r0 + rr) * 128 + t] = f2bf(a - bf2f(hb));
        float sq = a * a;
#pragma unroll
        for (int o = 1; o < 64; o <<= 1) sq += __shfl_xor(sq, o);
        if ((t & 63) == 0) red[(t >> 6) * 8 + rr] = sq;
    }
    __syncthreads();
    if (t < 8) hn[r0 + t] = 0.5f * (red[t] + red[8 + t]);
}

// log2 of the three prob vectors into one combined buffer
__global__ void k_log_all(const float* __restrict__ h, const float* __restrict__ hi,
                          const float* __restrict__ hj, float* __restrict__ lg)
{
    int i = blockIdx.x * 256 + threadIdx.x;   // 8192 total
    float x;
    if (i < 4096)      x = h[i];
    else if (i < 6144) x = hi[i - 4096];
    else               x = hj[i - 6144];
    lg[i] = __log2f(x);
}

// ------------------------------ cost GEMM (MFMA) ---------------------------
// C[i][j] = max(hna[i] + hnb[j] - dot(A_i, B_j), 0), dot via bf16 split:
// hh + hl + lh passes accumulate in one f32 acc (lo*lo dropped, ~2e-3 abs).
struct CostPair {
    const unsigned short *Ah, *Al, *Bh, *Bl;
    const float *hna, *hnb;
    float* C; int ldc;
};

__global__ __launch_bounds__(256)
void k_cost_mfma(CostPair P0, CostPair P1)
{
    CostPair P = blockIdx.z ? P1 : P0;
    const int i0 = blockIdx.y * 128, j0 = blockIdx.x * 128;
    const int w = threadIdx.x >> 6, lane = threadIdx.x & 63;
    const int ar = i0 + (w >> 1) * 64;
    const int bc = j0 + (w & 1) * 64;
    const int lrow = lane & 15;
    const int kgrp = (lane >> 4) * 8;

    f32x4 acc[4][4];
#pragma unroll
    for (int a = 0; a < 4; ++a)
#pragma unroll
        for (int c = 0; c < 4; ++c) acc[a][c] = (f32x4){0.f, 0.f, 0.f, 0.f};

    const unsigned short* Ap[3] = { P.Ah, P.Ah, P.Al };
    const unsigned short* Bp[3] = { P.Bh, P.Bl, P.Bh };
#pragma unroll
    for (int pass = 0; pass < 3; ++pass) {
        const unsigned short* Ab = Ap[pass];
        const unsigned short* Bb = Bp[pass];
#pragma unroll
        for (int kc = 0; kc < 128; kc += 32) {
            short8 a[4], b[4];
#pragma unroll
            for (int f = 0; f < 4; ++f) {
                a[f] = *reinterpret_cast<const short8*>(Ab + (size_t)(ar + f * 16 + lrow) * 128 + kc + kgrp);
                b[f] = *reinterpret_cast<const short8*>(Bb + (size_t)(bc + f * 16 + lrow) * 128 + kc + kgrp);
            }
#pragma unroll
            for (int fi = 0; fi < 4; ++fi)
#pragma unroll
                for (int fj = 0; fj < 4; ++fj)
                    acc[fi][fj] = __builtin_amdgcn_mfma_f32_16x16x32_bf16(a[fi], b[fj], acc[fi][fj], 0, 0, 0);
        }
    }
    // epilogue: C/D layout col = lane&15, row = (lane>>4)*4 + reg  [m89]
    const int erow = (lane >> 4) * 4, ecol = lane & 15;
#pragma unroll
    for (int fi = 0; fi < 4; ++fi) {
        int r0 = ar + fi * 16 + erow;
        f32x4 ha = *reinterpret_cast<const f32x4*>(P.hna + r0);
#pragma unroll
        for (int fj = 0; fj < 4; ++fj) {
            int c = bc + fj * 16 + ecol;
            float hb = P.hnb[c];
#pragma unroll
            for (int e = 0; e < 4; ++e) {
                float val = fmaxf(ha[e] + hb - acc[fi][fj][e], 0.f);
                P.C[(size_t)(r0 + e) * P.ldc + c] = val;
            }
        }
    }
}

// ------------------------------ transpose ----------------------------------
__global__ __launch_bounds__(256)
void k_transpose_big(const float* __restrict__ S0, float* __restrict__ D0,
                     const float* __restrict__ S1, float* __restrict__ D1,
                     int rows, int cols)
{
    const float* S = blockIdx.z ? S1 : S0;
    float* Dst     = blockIdx.z ? D1 : D0;
    __shared__ float t[64][65];
    const int r0 = blockIdx.y * 64, c0 = blockIdx.x * 64;
    const int tid = threadIdx.x;
#pragma unroll
    for (int p = 0; p < 4; ++p) {
        int q = tid + p * 256; int r = q >> 4, c4 = q & 15;
        float4 v = *reinterpret_cast<const float4*>(S + (size_t)(r0 + r) * cols + c0 + c4 * 4);
        t[r][c4 * 4 + 0] = v.x; t[r][c4 * 4 + 1] = v.y;
        t[r][c4 * 4 + 2] = v.z; t[r][c4 * 4 + 3] = v.w;
    }
    __syncthreads();
#pragma unroll
    for (int p = 0; p < 4; ++p) {
        int q = tid + p * 256; int r = q >> 4, c4 = q & 15;
        float4 v;
        v.x = t[c4 * 4 + 0][r]; v.y = t[c4 * 4 + 1][r];
        v.z = t[c4 * 4 + 2][r]; v.w = t[c4 * 4 + 3][r];
        *reinterpret_cast<float4*>(Dst + (size_t)(c0 + r) * rows + r0 + c4 * 4) = v;
    }
}

// ------------------------------ round kernel -------------------------------
// Each wave: one row-LSE (log2 domain):  v_j = win[j] - C[row][j]*ie2
// out value vnew = alpha*fold + beta*(-eps*ln2*(m + log2 s))
// out weight for the dual task next round: wout = logself + vnew*ie2_next
struct RTask {
    const float* C; const float* win; const float* logself; const float* fold;
    float* vout; float* wout; int width; int blk0;
};
struct RArgs {
    RTask t[6];
    float ie2, epsln2, ie2n, alpha, beta;
};

__global__ __launch_bounds__(256)
void k_round(RArgs A)
{
    const int b = blockIdx.x;
    int ti = 5;
    if      (b < A.t[1].blk0) ti = 0;
    else if (b < A.t[2].blk0) ti = 1;
    else if (b < A.t[3].blk0) ti = 2;
    else if (b < A.t[4].blk0) ti = 3;
    else if (b < A.t[5].blk0) ti = 4;
    RTask T = A.t[ti];
    const int w = threadIdx.x >> 6, lane = threadIdx.x & 63;
    const int row = (b - T.blk0) * 4 + w;
    const f32x4* C4 = reinterpret_cast<const f32x4*>(T.C + (size_t)row * T.width);
    const f32x4* W4 = reinterpret_cast<const f32x4*>(T.win);
    const int nf4 = T.width >> 2;
    const float ie2 = A.ie2;
    float m0 = -INFINITY, m1 = -INFINITY, m2 = -INFINITY, m3 = -INFINITY;
    float s0 = 0.f, s1 = 0.f, s2 = 0.f, s3 = 0.f;
    for (int it = lane; it < nf4; it += 64) {
        f32x4 c = C4[it], wv = W4[it];
        lse2_upd(m0, s0, fmaf(c[0], -ie2, wv[0]));
        lse2_upd(m1, s1, fmaf(c[1], -ie2, wv[1]));
        lse2_upd(m2, s2, fmaf(c[2], -ie2, wv[2]));
        lse2_upd(m3, s3, fmaf(c[3], -ie2, wv[3]));
    }
    lse2_merge(m0, s0, m1, s1);
    lse2_merge(m2, s2, m3, s3);
    lse2_merge(m0, s0, m2, s2);
#pragma unroll
    for (int o = 1; o < 64; o <<= 1) {
        float mo = __shfl_xor(m0, o), so = __shfl_xor(s0, o);
        lse2_merge(m0, s0, mo, so);
    }
    if (lane == 0) {
        float val  = -A.epsln2 * (m0 + __log2f(s0));
        float vnew = A.alpha * T.fold[row] + A.beta * val;
        T.vout[row] = vnew;
        T.wout[row] = fmaf(vnew, A.ie2n, T.logself[row]);
    }
}

// ------------------------------ final reduce -------------------------------
__global__ __launch_bounds__(1024)
void k_final(const float* __restrict__ h, const float* __restrict__ hi,
             const float* __restrict__ hj,
             const float* __restrict__ f1f, const float* __restrict__ f2f,
             const float* __restrict__ g1f, const float* __restrict__ gb1f,
             const float* __restrict__ g2f, const float* __restrict__ gb2f,
             int N, int M, float* __restrict__ out)
{
    float acc = 0.f;
    for (int i = threadIdx.x; i < N; i += 1024)
        acc += h[i] * (f2f[i] - f1f[i]);
    for (int j = threadIdx.x; j < M; j += 1024)
        acc += hj[j] * (g2f[j] - gb2f[j]) - hi[j] * (g1f[j] - gb1f[j]);
#pragma unroll
    for (int o = 32; o; o >>= 1) acc += __shfl_xor(acc, o);
    __shared__ float red[16];
    const int lane = threadIdx.x & 63, w = threadIdx.x >> 6;
    if (lane == 0) red[w] = acc;
    __syncthreads();
    if (threadIdx.x == 0) {
        float t = 0.f;
        for (int q = 0; q < 16; ++q) t += red[q];
        out[0] = 1.f / (1.f + expf(-t));   // SCALING_FACTOR = 1
    }
}

// ------------------------------ orchestration ------------------------------

extern "C" void kernel_launch(void* const* d_in, const int* in_sizes, int n_in,
                              void* d_out, int out_size, void* d_ws, size_t ws_size,
                              hipStream_t stream)
{
    const float* d  = (const float*)d_in[0];
    const float* si = (const float*)d_in[1];
    const float* sj = (const float*)d_in[2];
    const float* h  = (const float*)d_in[3];
    const float* hi = (const float*)d_in[4];
    const float* hj = (const float*)d_in[5];
    const float* W  = (const float*)d_in[6];
    float* out = (float*)d_out;

    const int N = 4096, M = 2048;
    (void)in_sizes; (void)n_in; (void)out_size; (void)ws_size;

    float* ws = (float*)d_ws;
    size_t off = 0;
    auto alloc = [&](size_t n) { float* p = ws + off; off += (n + 63) & ~(size_t)63; return p; };

    float* WT    = alloc(128 * 128);
    float* lg2   = alloc(8192);          // la2 | lbi2 | lbj2
    float* hnAll = alloc(8192);          // hnx | hni | hnj
    unsigned short* thAll = (unsigned short*)alloc(8192 * 128 / 2);
    unsigned short* tlAll = (unsigned short*)alloc(8192 * 128 / 2);
    float* f1[2]  = { alloc(N), alloc(N) };
    float* f2[2]  = { alloc(N), alloc(N) };
    float* g1[2]  = { alloc(M), alloc(M) };
    float* g2[2]  = { alloc(M), alloc(M) };
    float* gb1[2] = { alloc(M), alloc(M) };
    float* gb2[2] = { alloc(M), alloc(M) };
    float* WA1[2] = { alloc(N), alloc(N) };
    float* WA2[2] = { alloc(N), alloc(N) };
    float* WB1[2] = { alloc(M), alloc(M) };
    float* WB2[2] = { alloc(M), alloc(M) };
    float* WY1[2] = { alloc(M), alloc(M) };
    float* WY2[2] = { alloc(M), alloc(M) };
    float* f1f = alloc(N); float* f2f = alloc(N);
    float* g1f = alloc(M); float* g2f = alloc(M);
    float* gb1f = alloc(M); float* gb2f = alloc(M);
    float* C1  = alloc((size_t)N * M);
    float* C2  = alloc((size_t)N * M);
    float* CT1 = alloc((size_t)M * N);
    float* CT2 = alloc((size_t)M * N);
    float* Cy1 = alloc((size_t)M * M);
    float* Cy2 = alloc((size_t)M * M);

    float* la2  = lg2;
    float* lbi2 = lg2 + 4096;
    float* lbj2 = lg2 + 6144;
    const float* hnx = hnAll;
    const float* hni = hnAll + 4096;
    const float* hnj = hnAll + 6144;
    const unsigned short* tdh  = thAll;
    const unsigned short* tdl  = tlAll;
    const unsigned short* tsih = thAll + (size_t)4096 * 128;
    const unsigned short* tsil = tlAll + (size_t)4096 * 128;
    const unsigned short* tsjh = thAll + (size_t)6144 * 128;
    const unsigned short* tsjl = tlAll + (size_t)6144 * 128;

    // ---- setup ----
    k_transposeW<<<128, 128, 0, stream>>>(W, WT);
    k_transform_all<<<1024, 128, 0, stream>>>(d, si, sj, WT, thAll, tlAll, hnAll);
    k_log_all<<<32, 256, 0, stream>>>(h, hi, hj, lg2);

    // ---- cost matrices ----
    CostPair cx0 = { tdh, tdl, tsih, tsil, hnx, hni, C1, M };
    CostPair cx1 = { tdh, tdl, tsjh, tsjl, hnx, hnj, C2, M };
    k_cost_mfma<<<dim3(M / 128, N / 128, 2), 256, 0, stream>>>(cx0, cx1);
    CostPair cy0 = { tsih, tsil, tsih, tsil, hni, hni, Cy1, M };
    CostPair cy1 = { tsjh, tsjl, tsjh, tsjl, hnj, hnj, Cy2, M };
    k_cost_mfma<<<dim3(M / 128, M / 128, 2), 256, 0, stream>>>(cy0, cy1);
    k_transpose_big<<<dim3(M / 64, N / 64, 2), 256, 0, stream>>>(C1, CT1, C2, CT2, N, M);

    // ---- eps schedule ----
    double epsl[16]; int ne = 0;
    for (double sg = 32.0; sg > 0.05; sg *= 0.5) epsl[ne++] = sg * sg;
    epsl[ne++] = 0.05 * 0.05;   // ne == 11

    for (int r = 0; r <= ne + 1; ++r) {
        const bool init = (r == 0), fin = (r == ne + 1);
        const double eps  = init ? epsl[0] : (fin ? epsl[ne - 1] : epsl[r - 1]);
        const double epsn = (r + 1 <= ne) ? epsl[r] : epsl[ne - 1];
        const int in  = init ? 0 : (r - 1) & 1;
        const int o   = r & 1;

        RArgs A;
        A.ie2    = (float)(LOG2E / eps);
        A.epsln2 = (float)(eps * LN2);
        A.ie2n   = (float)(LOG2E / epsn);
        A.alpha  = (init || fin) ? 0.0f : 0.5f;
        A.beta   = (init || fin) ? 1.0f : 0.5f;
        A.t[0] = { C1,  init ? lbi2 : WB1[in], la2,  f1[in],  fin ? f1f  : f1[o],  WA1[o], M,    0 };
        A.t[1] = { C2,  init ? lbj2 : WB2[in], la2,  f2[in],  fin ? f2f  : f2[o],  WA2[o], M, 1024 };
        A.t[2] = { Cy1, init ? lbi2 : WY1[in], lbi2, gb1[in], fin ? gb1f : gb1[o], WY1[o], M, 2048 };
        A.t[3] = { Cy2, init ? lbj2 : WY2[in], lbj2, gb2[in], fin ? gb2f : gb2[o], WY2[o], M, 2560 };
        A.t[4] = { CT1, init ? la2  : WA1[in], lbi2, g1[in],  fin ? g1f  : g1[o],  WB1[o], N, 3072 };
        A.t[5] = { CT2, init ? la2  : WA2[in], lbj2, g2[in],  fin ? g2f  : g2[o],  WB2[o], N, 3584 };
        k_round<<<4096, 256, 0, stream>>>(A);
    }

    k_final<<<1, 1024, 0, stream>>>(h, hi, hj, f1f, f2f, g1f, gb1f, g2f, gb2f, N, M, out);
}